// Round 1
// baseline (274.401 us; speedup 1.0000x reference)
//
#include <hip/hip_runtime.h>
#include <math.h>

namespace {

constexpr int   kB     = 16;
constexpr int   kA     = 65536;
constexpr int   kM     = 32;
constexpr int   kC     = 20;
constexpr float kImg   = 600.0f;
constexpr int   kBlock = 256;

__device__ __forceinline__ float smooth_l1(float d) {
    float ad = fabsf(d);
    return ad < 1.0f ? 0.5f * d * d : ad - 0.5f;
}

__global__ __launch_bounds__(kBlock) void retina_main(
    const float* __restrict__ loc_preds,   // [B, A, 4]
    const float* __restrict__ cls_preds,   // [B, A, C]
    const float* __restrict__ iou_boxes,   // [A, 4] xywh
    const float* __restrict__ targets,     // [B*M, 6]
    float* __restrict__ acc)               // acc[0]=loc_sum acc[1]=cls_sum acc[2]=num_pos
{
    __shared__ float4 sbox[kM];           // x1, y1, x2+1, y2+1 (pixels)
    __shared__ float4 sxywh[kM];          // cx, cy, w, h (pixels)
    __shared__ int    slab[kM];
    __shared__ float  sred[3][kBlock / 64];

    const int b = blockIdx.y;
    const int a = blockIdx.x * kBlock + threadIdx.x;

    if (threadIdx.x < kM) {
        const float* t = targets + ((size_t)(b * kM + threadIdx.x)) * 6;
        float cx = t[2] * kImg, cy = t[3] * kImg;
        float w  = t[4] * kImg, h  = t[5] * kImg;
        float x1 = cx - w * 0.5f, y1 = cy - h * 0.5f;
        float x2 = cx + w * 0.5f, y2 = cy + h * 0.5f;
        sbox[threadIdx.x]  = make_float4(x1, y1, x2 + 1.0f, y2 + 1.0f);
        sxywh[threadIdx.x] = make_float4(cx, cy, w, h);
        slab[threadIdx.x]  = (int)t[1];
    }
    __syncthreads();

    // Anchor (coalesced float4 load)
    const float4 an  = *(const float4*)(iou_boxes + (size_t)a * 4);
    const float ax1  = an.x - an.z * 0.5f;
    const float ay1  = an.y - an.w * 0.5f;
    const float ax2p = an.x + an.z * 0.5f + 1.0f;  // x2 + 1
    const float ay2p = an.y + an.w * 0.5f + 1.0f;  // y2 + 1
    const float aarea = (ax2p - ax1) * (ay2p - ay1);

    // IoU argmax over M targets (first-max semantics like jnp.argmax)
    float best = -1.0f;
    int   mid  = 0;
#pragma unroll
    for (int m = 0; m < kM; ++m) {
        float4 q = sbox[m];
        float lx = fmaxf(ax1, q.x);
        float ly = fmaxf(ay1, q.y);
        float rx = fminf(ax2p, q.z);   // min(x2) + 1
        float ry = fminf(ay2p, q.w);
        float w  = fmaxf(rx - lx, 0.0f);
        float h  = fmaxf(ry - ly, 0.0f);
        float inter = w * h;
        float uni   = aarea + (q.z - q.x) * (q.w - q.y) - inter;
        float iou   = inter * __builtin_amdgcn_rcpf(uni);
        if (iou > best) { best = iou; mid = m; }
    }

    const bool pos    = best >= 0.5f;
    const bool ignore = (best > 0.4f) && (best < 0.5f);

    float loc_sum = 0.0f, cls_sum = 0.0f, npos = 0.0f;

    // ---- SmoothL1 over positive anchors (predicated: skips loc_preds read) ----
    if (pos) {
        npos = 1.0f;
        float4 mb  = sxywh[mid];
        float ltx = (mb.x - an.x) / an.z;
        float lty = (mb.y - an.y) / an.w;
        float ltw = __logf(mb.z / an.z);
        float lth = __logf(mb.w / an.w);
        float4 lp = *(const float4*)(loc_preds + ((size_t)b * kA + a) * 4);
        loc_sum = smooth_l1(lp.x - ltx) + smooth_l1(lp.y - lty) +
                  smooth_l1(lp.z - ltw) + smooth_l1(lp.w - lth);
    }

    // ---- Focal loss over non-ignored anchors ----
    if (!ignore) {
        const int tgt = pos ? (slab[mid] + 1) : 0;  // 0 = background
        const float* cp = cls_preds + ((size_t)b * kA + a) * kC;
#pragma unroll
        for (int i = 0; i < kC / 4; ++i) {
            float4 v = *(const float4*)(cp + i * 4);
            float xs[4] = {v.x, v.y, v.z, v.w};
#pragma unroll
            for (int j = 0; j < 4; ++j) {
                float x  = xs[j];
                bool  t  = (i * 4 + j + 1) == tgt;
                float e  = __expf(-fabsf(x));                       // exp(-|x|)
                float r  = __builtin_amdgcn_rcpf(1.0f + e);         // sigmoid(|x|)
                float p  = (x >= 0.0f) ? r : 1.0f - r;              // sigmoid(x)
                float sp = __logf(1.0f + e) + fmaxf(x, 0.0f);       // softplus(x)
                float pt  = t ? p : 1.0f - p;
                float omp = 1.0f - pt;
                float wgt = (t ? 0.25f : 0.75f) * omp * omp;
                float bce = sp - (t ? x : 0.0f);
                cls_sum += wgt * bce;
            }
        }
    }

    // ---- Reduce: wave shuffle -> LDS -> one atomic per block ----
#pragma unroll
    for (int off = 32; off > 0; off >>= 1) {
        loc_sum += __shfl_down(loc_sum, off);
        cls_sum += __shfl_down(cls_sum, off);
        npos    += __shfl_down(npos, off);
    }
    const int lane = threadIdx.x & 63;
    const int wid  = threadIdx.x >> 6;
    if (lane == 0) {
        sred[0][wid] = loc_sum;
        sred[1][wid] = cls_sum;
        sred[2][wid] = npos;
    }
    __syncthreads();
    if (threadIdx.x == 0) {
        float l = 0.0f, c = 0.0f, n = 0.0f;
#pragma unroll
        for (int i = 0; i < kBlock / 64; ++i) {
            l += sred[0][i]; c += sred[1][i]; n += sred[2][i];
        }
        atomicAdd(acc + 0, l);
        atomicAdd(acc + 1, c);
        atomicAdd(acc + 2, n);
    }
}

__global__ void retina_final(const float* __restrict__ acc, float* __restrict__ out) {
    float loc = acc[0], cls = acc[1];
    float np  = fmaxf(1.0f, acc[2]);
    float inv = 1.0f / np;
    out[0] = (loc + cls) * inv;
    out[1] = loc * inv;
    out[2] = cls * inv;
}

}  // namespace

extern "C" void kernel_launch(void* const* d_in, const int* in_sizes, int n_in,
                              void* d_out, int out_size, void* d_ws, size_t ws_size,
                              hipStream_t stream) {
    const float* loc_preds = (const float*)d_in[0];
    const float* cls_preds = (const float*)d_in[1];
    const float* iou_boxes = (const float*)d_in[2];
    const float* targets   = (const float*)d_in[3];
    float* out = (float*)d_out;
    float* acc = (float*)d_ws;

    hipMemsetAsync(acc, 0, 3 * sizeof(float), stream);

    dim3 grid(kA / kBlock, kB);
    retina_main<<<grid, kBlock, 0, stream>>>(loc_preds, cls_preds, iou_boxes, targets, acc);
    retina_final<<<1, 1, 0, stream>>>(acc, out);
}